// Round 4
// baseline (494.873 us; speedup 1.0000x reference)
//
#include <hip/hip_runtime.h>
#include <math.h>

// Sizes
#define NB 32
#define NL 512

// ws layout (floats):
// [0, 16384)            x_avg[b][l]
// [16384, 32768)        x_max[b][l]
// [32768, 32768+131072) ypart[c*2+half][b][l]   (8 slots of 16384)

__global__ __launch_bounds__(256) void kreduce(const float* __restrict__ in,
                                               float* __restrict__ xavg,
                                               float* __restrict__ xmax) {
    const int bl = blockIdx.x;            // 0..16383  (= b*512 + l)
    const float* p = in + (size_t)bl * 4096;
    const int t = threadIdx.x;
    float s = 0.f, m = -INFINITY;
#pragma unroll
    for (int it = 0; it < 4; ++it) {
        float4 v = *reinterpret_cast<const float4*>(p + (size_t)(it * 256 + t) * 4);
        s += v.x + v.y + v.z + v.w;
        m = fmaxf(m, fmaxf(fmaxf(v.x, v.y), fmaxf(v.z, v.w)));
    }
#pragma unroll
    for (int o = 1; o < 64; o <<= 1) {
        s += __shfl_xor(s, o);
        m = fmaxf(m, __shfl_xor(m, o));
    }
    __shared__ float ls[4], lm[4];
    const int w = t >> 6;
    if ((t & 63) == 0) { ls[w] = s; lm[w] = m; }
    __syncthreads();
    if (t == 0) {
        s = ls[0] + ls[1] + ls[2] + ls[3];
        m = fmaxf(fmaxf(lm[0], lm[1]), fmaxf(lm[2], lm[3]));
        xavg[bl] = s * (1.f / 4096.f);
        xmax[bl] = m;
    }
}

// DPP add over 16-lane rows: after shl 1,2,4,8 lane (s==0) of each row holds the row sum.
#define DPP_ADD(v, ctrl) ((v) + __int_as_float(__builtin_amdgcn_update_dpp(0, __float_as_int(v), (ctrl), 0xF, 0xF, true)))

// One block per (call c in 0..3, d-half, batch b). 512 threads.
__global__ __launch_bounds__(512) void kmamba(
    const float* __restrict__ xavg, const float* __restrict__ xmax,
    float* __restrict__ ypart,
    const float* __restrict__ paw, const float* __restrict__ pab,
    const float* __restrict__ pmw, const float* __restrict__ pmb,
    const float* __restrict__ outw_outer,
    const float* __restrict__ f_in_w, const float* __restrict__ f_conv_w, const float* __restrict__ f_conv_b,
    const float* __restrict__ f_xproj_w, const float* __restrict__ f_dt_w, const float* __restrict__ f_dt_b,
    const float* __restrict__ f_A_log, const float* __restrict__ f_D, const float* __restrict__ f_out_w,
    const float* __restrict__ b_in_w, const float* __restrict__ b_conv_w, const float* __restrict__ b_conv_b,
    const float* __restrict__ b_xproj_w, const float* __restrict__ b_dt_w, const float* __restrict__ b_dt_b,
    const float* __restrict__ b_A_log, const float* __restrict__ b_D, const float* __restrict__ b_out_w)
{
    const int tid = threadIdx.x;
    const int c = blockIdx.x >> 6;
    const int half = (blockIdx.x >> 5) & 1;
    const int b = blockIdx.x & 31;
    const int strm = c >> 1, dir = c & 1;

    const float* in_w = dir ? b_in_w   : f_in_w;
    const float* cwp  = dir ? b_conv_w : f_conv_w;
    const float* cbp  = dir ? b_conv_b : f_conv_b;
    const float* xpw  = dir ? b_xproj_w: f_xproj_w;
    const float* dtwp = dir ? b_dt_w   : f_dt_w;
    const float* dtbp = dir ? b_dt_b   : f_dt_b;
    const float* alog = dir ? b_A_log  : f_A_log;
    const float* Dpar = dir ? b_D      : f_D;
    const float* owp  = dir ? b_out_w  : f_out_w;
    const float* projw = strm ? pmw : paw;
    const float* projb = strm ? pmb : pab;
    const float* xin   = strm ? xmax : xavg;

    __shared__ float sseq[512];
    __shared__ float su[128], sv[128];
    __shared__ float swf[64];
    __shared__ float scw[64][4], scb[64], sdtw[64][2], sdtb[64], sD[64];
    __shared__ float sxp[34][68];     // staged xproj_w rows (dt0,dt1,B0..15,C0..15)
    __shared__ float sxi[64][68];     // xi for all 64 d, current chunk (row-major)
    __shared__ float sdtv[64][4];     // dt0,dt1 per row
    __shared__ float sbcT[32][68];    // B(0..15),C(16..31) transposed: [j][row]
    __shared__ float sdeltaT[32][68]; // own-half delta, transposed [dd][row]
    __shared__ float sdxvT[32][68];   // own-half delta*xi, transposed
    __shared__ float sgdT[32][68];    // own-half silu(z)*wfold, transposed
    __shared__ float syT[32][68];     // per-d scan output, transposed
    __shared__ float sybase[64];      // per-row Sum_d gd*D*xi (own half)
    __shared__ float shE[8][512];     // local chunk-end states
    __shared__ float shin[8][512];    // chunk incoming states
    __shared__ float sSd[8][32];      // per-chunk per-d sum of delta

    // one-time setup
    {
        int i = tid;
        int l = dir ? (511 - i) : i;
        sseq[i] = xin[b * 512 + l];
    }
    if (tid < 128) {
        float u = 0.f, v = 0.f;
        const float* row = in_w + tid * 32;
#pragma unroll
        for (int m = 0; m < 32; ++m) {
            u = fmaf(row[m], projw[m], u);
            v = fmaf(row[m], projb[m], v);
        }
        su[tid] = u; sv[tid] = v;
    }
    if (tid < 64) {
        int d = tid;
#pragma unroll
        for (int k = 0; k < 4; ++k) scw[d][k] = cwp[d * 4 + k];
        scb[d] = cbp[d];
        sdtw[d][0] = dtwp[d * 2];
        sdtw[d][1] = dtwp[d * 2 + 1];
        sdtb[d] = dtbp[d];
        sD[d] = Dpar[d];
        float wf = 0.f;
#pragma unroll
        for (int m = 0; m < 32; ++m) wf = fmaf(outw_outer[m], owp[m * 64 + d], wf);
        swf[d] = wf;
    }
    for (int i = tid; i < 34 * 64; i += 512) sxp[i >> 6][i & 63] = xpw[i];

    const int dd = tid >> 4;        // 0..31 (own-half local d)
    const int s  = tid & 15;        // state index
    const int d  = half * 32 + dd;  // global d
    const float cA = -expf(alog[d * 16 + s]) * 1.44269504088896340736f;

    const int ll8 = tid >> 3;       // 0..63 (phase-A row)
    const int j8  = tid & 7;

    __syncthreads();

    for (int sweep = 0; sweep < 2; ++sweep) {
        for (int chunk = 0; chunk < 8; ++chunk) {
            const int ibase = chunk * 64;

            // ---- A1: xi (post-conv, silu) for all 64 d ----
            {
                int i = ibase + ll8;
                float t0 = (i - 3 >= 0) ? sseq[i - 3] : 0.f;
                float t1 = (i - 2 >= 0) ? sseq[i - 2] : 0.f;
                float t2 = (i - 1 >= 0) ? sseq[i - 1] : 0.f;
                float t3 = sseq[i];
                float vv0 = (i - 3 >= 0) ? 1.f : 0.f;
                float vv1 = (i - 2 >= 0) ? 1.f : 0.f;
                float vv2 = (i - 1 >= 0) ? 1.f : 0.f;
#pragma unroll
                for (int k = 0; k < 8; ++k) {
                    int di = j8 * 8 + k;
                    float u = su[di], v = sv[di];
                    float xc = scw[di][0] * fmaf(t0, u, vv0 * v)
                             + scw[di][1] * fmaf(t1, u, vv1 * v)
                             + scw[di][2] * fmaf(t2, u, vv2 * v)
                             + scw[di][3] * fmaf(t3, u, v);
                    xc += scb[di];
                    float sig = 1.f / (1.f + __expf(-xc));
                    sxi[ll8][di] = xc * sig;
                }
            }
            __syncthreads();

            // ---- A2: dbc = xi @ xproj_w.T (34 outputs; w from LDS) ----
            {
                float a0 = 0.f, a1 = 0.f, a2 = 0.f, a3 = 0.f, a4 = 0.f;
                const float4* xr4 = reinterpret_cast<const float4*>(&sxi[ll8][0]);
                const float4* r0 = reinterpret_cast<const float4*>(&sxp[j8 + 0][0]);
                const float4* r1 = reinterpret_cast<const float4*>(&sxp[j8 + 8][0]);
                const float4* r2 = reinterpret_cast<const float4*>(&sxp[j8 + 16][0]);
                const float4* r3 = reinterpret_cast<const float4*>(&sxp[j8 + 24][0]);
                const float4* r4 = (j8 < 2) ? reinterpret_cast<const float4*>(&sxp[j8 + 32][0]) : r0;
                bool extra = (j8 < 2);
#pragma unroll
                for (int q = 0; q < 16; ++q) {
                    float4 x = xr4[q];
                    float4 w;
                    w = r0[q]; a0 = fmaf(x.x,w.x,fmaf(x.y,w.y,fmaf(x.z,w.z,fmaf(x.w,w.w,a0))));
                    w = r1[q]; a1 = fmaf(x.x,w.x,fmaf(x.y,w.y,fmaf(x.z,w.z,fmaf(x.w,w.w,a1))));
                    w = r2[q]; a2 = fmaf(x.x,w.x,fmaf(x.y,w.y,fmaf(x.z,w.z,fmaf(x.w,w.w,a2))));
                    w = r3[q]; a3 = fmaf(x.x,w.x,fmaf(x.y,w.y,fmaf(x.z,w.z,fmaf(x.w,w.w,a3))));
                    if (extra) { w = r4[q]; a4 = fmaf(x.x,w.x,fmaf(x.y,w.y,fmaf(x.z,w.z,fmaf(x.w,w.w,a4)))); }
                }
                // j = j8: 0,1 -> dt; 2..33 -> B/C transposed
                if (j8 < 2) sdtv[ll8][j8] = a0; else sbcT[j8 - 2][ll8] = a0;
                sbcT[j8 + 6][ll8]  = a1;
                sbcT[j8 + 14][ll8] = a2;
                sbcT[j8 + 22][ll8] = a3;
                if (extra) sbcT[j8 + 30][ll8] = a4;
            }
            __syncthreads();

            // ---- A3: delta, delta*xi, gate*wfold (own half, transposed); ybase ----
            {
                float dt0 = sdtv[ll8][0], dt1 = sdtv[ll8][1];
                float xl = sseq[ibase + ll8];
                float ybp = 0.f;
                bool own = ((j8 >> 2) == half);
#pragma unroll
                for (int k = 0; k < 8; ++k) {
                    int di = j8 * 8 + k;
                    float pre = fmaf(dt0, sdtw[di][0], fmaf(dt1, sdtw[di][1], sdtb[di]));
                    float sp = (pre > 20.f) ? pre : log1pf(__expf(pre));
                    if (own) {
                        int ddx = (j8 & 3) * 8 + k;
                        float xiv = sxi[ll8][di];
                        sdeltaT[ddx][ll8] = sp;
                        sdxvT[ddx][ll8] = sp * xiv;
                        float zv = fmaf(xl, su[64 + di], sv[64 + di]);
                        float sig = 1.f / (1.f + __expf(-zv));
                        float gd = (zv * sig) * swf[di];
                        sgdT[ddx][ll8] = gd;
                        ybp = fmaf(gd * sD[di], xiv, ybp);
                    }
                }
                ybp += __shfl_xor(ybp, 1);
                ybp += __shfl_xor(ybp, 2);
                ybp += __shfl_xor(ybp, 4);
                if (j8 == 0) sybase[ll8] = ybp;
            }
            __syncthreads();

            if (sweep == 0) {
                // ---- B1: h-only local scan (h_in = 0), summaries ----
                float h = 0.f, Sd = 0.f;
                const float4* dT = reinterpret_cast<const float4*>(&sdeltaT[dd][0]);
                const float4* xT = reinterpret_cast<const float4*>(&sdxvT[dd][0]);
                const float4* bT = reinterpret_cast<const float4*>(&sbcT[s][0]);
#pragma unroll 4
                for (int m = 0; m < 16; ++m) {
                    float4 de = dT[m], dx = xT[m], Bq = bT[m];
                    float a;
                    a = exp2f(de.x * cA); h = fmaf(a, h, dx.x * Bq.x);
                    a = exp2f(de.y * cA); h = fmaf(a, h, dx.y * Bq.y);
                    a = exp2f(de.z * cA); h = fmaf(a, h, dx.z * Bq.z);
                    a = exp2f(de.w * cA); h = fmaf(a, h, dx.w * Bq.w);
                    Sd += de.x + de.y + de.z + de.w;
                }
                shE[chunk][tid] = h;
                if (s == 0) sSd[chunk][dd] = Sd;
                __syncthreads();
            } else {
                // ---- B3: full scan seeded with h_in; y per (d,t) ----
                float h = shin[chunk][tid];
                const float4* dT = reinterpret_cast<const float4*>(&sdeltaT[dd][0]);
                const float4* xT = reinterpret_cast<const float4*>(&sdxvT[dd][0]);
                const float4* bT = reinterpret_cast<const float4*>(&sbcT[s][0]);
                const float4* cT = reinterpret_cast<const float4*>(&sbcT[16 + s][0]);
                const float4* gT = reinterpret_cast<const float4*>(&sgdT[dd][0]);
#pragma unroll 2
                for (int m = 0; m < 16; ++m) {
                    float4 de = dT[m], dx = xT[m], Bq = bT[m], Cq = cT[m], gq = gT[m];
                    float4 val;
                    float a, pc;
                    a = exp2f(de.x * cA); h = fmaf(a, h, dx.x * Bq.x); pc = h * Cq.x;
                    pc = DPP_ADD(pc, 0x101); pc = DPP_ADD(pc, 0x102);
                    pc = DPP_ADD(pc, 0x104); pc = DPP_ADD(pc, 0x108);
                    val.x = pc * gq.x;
                    a = exp2f(de.y * cA); h = fmaf(a, h, dx.y * Bq.y); pc = h * Cq.y;
                    pc = DPP_ADD(pc, 0x101); pc = DPP_ADD(pc, 0x102);
                    pc = DPP_ADD(pc, 0x104); pc = DPP_ADD(pc, 0x108);
                    val.y = pc * gq.y;
                    a = exp2f(de.z * cA); h = fmaf(a, h, dx.z * Bq.z); pc = h * Cq.z;
                    pc = DPP_ADD(pc, 0x101); pc = DPP_ADD(pc, 0x102);
                    pc = DPP_ADD(pc, 0x104); pc = DPP_ADD(pc, 0x108);
                    val.z = pc * gq.z;
                    a = exp2f(de.w * cA); h = fmaf(a, h, dx.w * Bq.w); pc = h * Cq.w;
                    pc = DPP_ADD(pc, 0x101); pc = DPP_ADD(pc, 0x102);
                    pc = DPP_ADD(pc, 0x104); pc = DPP_ADD(pc, 0x108);
                    val.w = pc * gq.w;
                    if (s == 0) *reinterpret_cast<float4*>(&syT[dd][4 * m]) = val;
                }
                __syncthreads();

                // ---- C: fold over own-half d, write partial ----
                {
                    float acc = 0.f;
#pragma unroll
                    for (int k = 0; k < 4; ++k) {
                        acc += syT[j8 * 4 + k][ll8];
                    }
                    acc += __shfl_xor(acc, 1);
                    acc += __shfl_xor(acc, 2);
                    acc += __shfl_xor(acc, 4);
                    if (j8 == 0) {
                        int i = ibase + ll8;
                        int l = dir ? (511 - i) : i;
                        ypart[((c * 2 + half) * 32 + b) * 512 + l] = acc + sybase[ll8];
                    }
                }
                __syncthreads();
            }
        }

        if (sweep == 0) {
            // ---- B2: combine chunk summaries -> incoming states ----
            float hcur = 0.f;
#pragma unroll
            for (int k = 0; k < 8; ++k) {
                shin[k][tid] = hcur;
                float aP = exp2f(cA * sSd[k][dd]);
                hcur = fmaf(aP, hcur, shE[k][tid]);
            }
            __syncthreads();
        }
    }
}

__global__ __launch_bounds__(256) void kfinal(const float* __restrict__ xavg,
                                              const float* __restrict__ xmax,
                                              const float* __restrict__ ypart,
                                              const float* __restrict__ gate_w,
                                              const float* __restrict__ gate_b,
                                              const float* __restrict__ out_b,
                                              float* __restrict__ out) {
    const int idx = blockIdx.x * 256 + threadIdx.x;   // 0..16383
    float xa = xavg[idx], xm = xmax[idx];
    float alpha = 1.f / (1.f + __expf(-(fmaf(xa, gate_w[0], fmaf(xm, gate_w[1], gate_b[0])))));
    float sa = ypart[0 * 16384 + idx] + ypart[1 * 16384 + idx]
             + ypart[2 * 16384 + idx] + ypart[3 * 16384 + idx];
    float sm = ypart[4 * 16384 + idx] + ypart[5 * 16384 + idx]
             + ypart[6 * 16384 + idx] + ypart[7 * 16384 + idx];
    float y = alpha * sa + (1.f - alpha) * sm + out_b[0];
    out[idx] = 1.f / (1.f + __expf(-y));
}

extern "C" void kernel_launch(void* const* d_in, const int* in_sizes, int n_in,
                              void* d_out, int out_size, void* d_ws, size_t ws_size,
                              hipStream_t stream) {
    const float* inp = (const float*)d_in[0];
    const float* paw = (const float*)d_in[1];
    const float* pab = (const float*)d_in[2];
    const float* pmw = (const float*)d_in[3];
    const float* pmb = (const float*)d_in[4];
    const float* gw  = (const float*)d_in[5];
    const float* gb  = (const float*)d_in[6];
    const float* ow  = (const float*)d_in[7];
    const float* ob  = (const float*)d_in[8];

    float* ws = (float*)d_ws;
    float* xavg = ws;
    float* xmax = ws + 16384;
    float* ypart = ws + 32768;
    float* out = (float*)d_out;

    kreduce<<<16384, 256, 0, stream>>>(inp, xavg, xmax);
    kmamba<<<256, 512, 0, stream>>>(
        xavg, xmax, ypart, paw, pab, pmw, pmb, ow,
        (const float*)d_in[9],  (const float*)d_in[10], (const float*)d_in[11],
        (const float*)d_in[12], (const float*)d_in[13], (const float*)d_in[14],
        (const float*)d_in[15], (const float*)d_in[16], (const float*)d_in[17],
        (const float*)d_in[18], (const float*)d_in[19], (const float*)d_in[20],
        (const float*)d_in[21], (const float*)d_in[22], (const float*)d_in[23],
        (const float*)d_in[24], (const float*)d_in[25], (const float*)d_in[26]);
    kfinal<<<64, 256, 0, stream>>>(xavg, xmax, ypart, gw, gb, ob, out);
}

// Round 5
// 284.603 us; speedup vs baseline: 1.7388x; 1.7388x over previous
//
#include <hip/hip_runtime.h>
#include <math.h>

// Sizes
#define NB 32
#define NL 512

// ws layout (floats):
// [0, 16384)            x_avg[b][l]
// [16384, 32768)        x_max[b][l]
// [32768, 32768+131072) ypart[c*2+half][b][l]   (8 slots of 16384)

__global__ __launch_bounds__(256) void kreduce(const float* __restrict__ in,
                                               float* __restrict__ xavg,
                                               float* __restrict__ xmax) {
    const int bl = blockIdx.x;            // 0..16383  (= b*512 + l)
    const float* p = in + (size_t)bl * 4096;
    const int t = threadIdx.x;
    float s = 0.f, m = -INFINITY;
#pragma unroll
    for (int it = 0; it < 4; ++it) {
        float4 v = *reinterpret_cast<const float4*>(p + (size_t)(it * 256 + t) * 4);
        s += v.x + v.y + v.z + v.w;
        m = fmaxf(m, fmaxf(fmaxf(v.x, v.y), fmaxf(v.z, v.w)));
    }
#pragma unroll
    for (int o = 1; o < 64; o <<= 1) {
        s += __shfl_xor(s, o);
        m = fmaxf(m, __shfl_xor(m, o));
    }
    __shared__ float ls[4], lm[4];
    const int w = t >> 6;
    if ((t & 63) == 0) { ls[w] = s; lm[w] = m; }
    __syncthreads();
    if (t == 0) {
        s = ls[0] + ls[1] + ls[2] + ls[3];
        m = fmaxf(fmaxf(lm[0], lm[1]), fmaxf(lm[2], lm[3]));
        xavg[bl] = s * (1.f / 4096.f);
        xmax[bl] = m;
    }
}

// DPP add over 16-lane rows: after shl 1,2,4,8, lane (s==0) of each row holds the row sum.
// (verified empirically: round-4 kernel passed with absmax 0.0 using this chain)
#define DPP_ADD(v, ctrl) ((v) + __int_as_float(__builtin_amdgcn_update_dpp(0, __float_as_int(v), (ctrl), 0xF, 0xF, true)))

// One block per (call c in 0..3, d-half, batch b). 512 threads.
// __launch_bounds__(512, 2): 2 waves/EU = 1 block/CU target -> 256-VGPR budget, no spill.
__global__ __launch_bounds__(512, 2) void kmamba(
    const float* __restrict__ xavg, const float* __restrict__ xmax,
    float* __restrict__ ypart,
    const float* __restrict__ paw, const float* __restrict__ pab,
    const float* __restrict__ pmw, const float* __restrict__ pmb,
    const float* __restrict__ outw_outer,
    const float* __restrict__ f_in_w, const float* __restrict__ f_conv_w, const float* __restrict__ f_conv_b,
    const float* __restrict__ f_xproj_w, const float* __restrict__ f_dt_w, const float* __restrict__ f_dt_b,
    const float* __restrict__ f_A_log, const float* __restrict__ f_D, const float* __restrict__ f_out_w,
    const float* __restrict__ b_in_w, const float* __restrict__ b_conv_w, const float* __restrict__ b_conv_b,
    const float* __restrict__ b_xproj_w, const float* __restrict__ b_dt_w, const float* __restrict__ b_dt_b,
    const float* __restrict__ b_A_log, const float* __restrict__ b_D, const float* __restrict__ b_out_w)
{
    const int tid = threadIdx.x;
    const int c = blockIdx.x >> 6;
    const int half = (blockIdx.x >> 5) & 1;
    const int b = blockIdx.x & 31;
    const int strm = c >> 1, dir = c & 1;

    const float* in_w = dir ? b_in_w   : f_in_w;
    const float* cwp  = dir ? b_conv_w : f_conv_w;
    const float* cbp  = dir ? b_conv_b : f_conv_b;
    const float* xpw  = dir ? b_xproj_w: f_xproj_w;
    const float* dtwp = dir ? b_dt_w   : f_dt_w;
    const float* dtbp = dir ? b_dt_b   : f_dt_b;
    const float* alog = dir ? b_A_log  : f_A_log;
    const float* Dpar = dir ? b_D      : f_D;
    const float* owp  = dir ? b_out_w  : f_out_w;
    const float* projw = strm ? pmw : paw;
    const float* projb = strm ? pmb : pab;
    const float* xin   = strm ? xmax : xavg;

    __shared__ float sseq[512];
    __shared__ float su[128], sv[128];
    __shared__ float swf[64];
    __shared__ float scw[64][4], scb[64], sdtw[64][2], sdtb[64], sD[64];
    __shared__ float sxp[34][68];     // staged xproj_w rows (dt0,dt1,B0..15,C0..15)
    __shared__ float sxi[64][68];     // xi for all 64 d, current chunk (row-major)
    __shared__ float sdtv[64][4];     // dt0,dt1 per row
    __shared__ float sbcT[32][68];    // B(0..15),C(16..31) transposed: [j][row]
    __shared__ float sdeltaT[32][68]; // own-half delta, transposed [dd][row]
    __shared__ float sdxvT[32][68];   // own-half delta*xi, transposed
    __shared__ float sgdT[32][68];    // own-half silu(z)*wfold, transposed
    __shared__ float syT[32][68];     // per-d scan output, transposed
    __shared__ float sybase[64];      // per-row Sum_d gd*D*xi (own half)

    // one-time setup
    {
        int i = tid;
        int l = dir ? (511 - i) : i;
        sseq[i] = xin[b * 512 + l];
    }
    if (tid < 128) {
        float u = 0.f, v = 0.f;
        const float* row = in_w + tid * 32;
#pragma unroll
        for (int m = 0; m < 32; ++m) {
            u = fmaf(row[m], projw[m], u);
            v = fmaf(row[m], projb[m], v);
        }
        su[tid] = u; sv[tid] = v;
    }
    if (tid < 64) {
        int d = tid;
#pragma unroll
        for (int k = 0; k < 4; ++k) scw[d][k] = cwp[d * 4 + k];
        scb[d] = cbp[d];
        sdtw[d][0] = dtwp[d * 2];
        sdtw[d][1] = dtwp[d * 2 + 1];
        sdtb[d] = dtbp[d];
        sD[d] = Dpar[d];
        float wf = 0.f;
#pragma unroll
        for (int m = 0; m < 32; ++m) wf = fmaf(outw_outer[m], owp[m * 64 + d], wf);
        swf[d] = wf;
    }
    for (int i = tid; i < 34 * 64; i += 512) sxp[i >> 6][i & 63] = xpw[i];

    const int dd = tid >> 4;        // 0..31 (own-half local d)
    const int s  = tid & 15;        // state index
    const int d  = half * 32 + dd;  // global d
    const float cA = -expf(alog[d * 16 + s]) * 1.44269504088896340736f;
    float h = 0.f;                  // carried across all 8 chunks in-register

    const int ll8 = tid >> 3;       // 0..63 (phase-A row)
    const int j8  = tid & 7;

    __syncthreads();

    for (int chunk = 0; chunk < 8; ++chunk) {
        const int ibase = chunk * 64;

        // ---- A1: xi (post-conv, silu) for all 64 d ----
        {
            int i = ibase + ll8;
            float t0 = (i - 3 >= 0) ? sseq[i - 3] : 0.f;
            float t1 = (i - 2 >= 0) ? sseq[i - 2] : 0.f;
            float t2 = (i - 1 >= 0) ? sseq[i - 1] : 0.f;
            float t3 = sseq[i];
            float vv0 = (i - 3 >= 0) ? 1.f : 0.f;
            float vv1 = (i - 2 >= 0) ? 1.f : 0.f;
            float vv2 = (i - 1 >= 0) ? 1.f : 0.f;
#pragma unroll
            for (int k = 0; k < 8; ++k) {
                int di = j8 * 8 + k;
                float u = su[di], v = sv[di];
                float xc = scw[di][0] * fmaf(t0, u, vv0 * v)
                         + scw[di][1] * fmaf(t1, u, vv1 * v)
                         + scw[di][2] * fmaf(t2, u, vv2 * v)
                         + scw[di][3] * fmaf(t3, u, v);
                xc += scb[di];
                float sig = 1.f / (1.f + __expf(-xc));
                sxi[ll8][di] = xc * sig;
            }
        }
        __syncthreads();

        // ---- A2: dbc = xi @ xproj_w.T (34 outputs; w from LDS) ----
        {
            float a0 = 0.f, a1 = 0.f, a2 = 0.f, a3 = 0.f, a4 = 0.f;
            const float4* xr4 = reinterpret_cast<const float4*>(&sxi[ll8][0]);
            const float4* r0 = reinterpret_cast<const float4*>(&sxp[j8 + 0][0]);
            const float4* r1 = reinterpret_cast<const float4*>(&sxp[j8 + 8][0]);
            const float4* r2 = reinterpret_cast<const float4*>(&sxp[j8 + 16][0]);
            const float4* r3 = reinterpret_cast<const float4*>(&sxp[j8 + 24][0]);
            const float4* r4 = (j8 < 2) ? reinterpret_cast<const float4*>(&sxp[j8 + 32][0]) : r0;
            bool extra = (j8 < 2);
#pragma unroll
            for (int q = 0; q < 16; ++q) {
                float4 x = xr4[q];
                float4 w;
                w = r0[q]; a0 = fmaf(x.x,w.x,fmaf(x.y,w.y,fmaf(x.z,w.z,fmaf(x.w,w.w,a0))));
                w = r1[q]; a1 = fmaf(x.x,w.x,fmaf(x.y,w.y,fmaf(x.z,w.z,fmaf(x.w,w.w,a1))));
                w = r2[q]; a2 = fmaf(x.x,w.x,fmaf(x.y,w.y,fmaf(x.z,w.z,fmaf(x.w,w.w,a2))));
                w = r3[q]; a3 = fmaf(x.x,w.x,fmaf(x.y,w.y,fmaf(x.z,w.z,fmaf(x.w,w.w,a3))));
                if (extra) { w = r4[q]; a4 = fmaf(x.x,w.x,fmaf(x.y,w.y,fmaf(x.z,w.z,fmaf(x.w,w.w,a4)))); }
            }
            // j = j8: 0,1 -> dt; 2..33 -> B/C transposed
            if (j8 < 2) sdtv[ll8][j8] = a0; else sbcT[j8 - 2][ll8] = a0;
            sbcT[j8 + 6][ll8]  = a1;
            sbcT[j8 + 14][ll8] = a2;
            sbcT[j8 + 22][ll8] = a3;
            if (extra) sbcT[j8 + 30][ll8] = a4;
        }
        __syncthreads();

        // ---- A3: delta, delta*xi, gate*wfold (own half, transposed); ybase ----
        {
            float dt0 = sdtv[ll8][0], dt1 = sdtv[ll8][1];
            float xl = sseq[ibase + ll8];
            float ybp = 0.f;
            bool own = ((j8 >> 2) == half);
#pragma unroll
            for (int k = 0; k < 8; ++k) {
                int di = j8 * 8 + k;
                float pre = fmaf(dt0, sdtw[di][0], fmaf(dt1, sdtw[di][1], sdtb[di]));
                float sp = (pre > 20.f) ? pre : log1pf(__expf(pre));
                if (own) {
                    int ddx = (j8 & 3) * 8 + k;
                    float xiv = sxi[ll8][di];
                    sdeltaT[ddx][ll8] = sp;
                    sdxvT[ddx][ll8] = sp * xiv;
                    float zv = fmaf(xl, su[64 + di], sv[64 + di]);
                    float sig = 1.f / (1.f + __expf(-zv));
                    float gd = (zv * sig) * swf[di];
                    sgdT[ddx][ll8] = gd;
                    ybp = fmaf(gd * sD[di], xiv, ybp);
                }
            }
            ybp += __shfl_xor(ybp, 1);
            ybp += __shfl_xor(ybp, 2);
            ybp += __shfl_xor(ybp, 4);
            if (j8 == 0) sybase[ll8] = ybp;
        }
        __syncthreads();

        // ---- B: scan 64 steps, h carried in-register across chunks ----
        {
            const float4* dT = reinterpret_cast<const float4*>(&sdeltaT[dd][0]);
            const float4* xT = reinterpret_cast<const float4*>(&sdxvT[dd][0]);
            const float4* bT = reinterpret_cast<const float4*>(&sbcT[s][0]);
            const float4* cT = reinterpret_cast<const float4*>(&sbcT[16 + s][0]);
            const float4* gT = reinterpret_cast<const float4*>(&sgdT[dd][0]);
#pragma unroll 2
            for (int m = 0; m < 16; ++m) {
                float4 de = dT[m], dx = xT[m], Bq = bT[m], Cq = cT[m], gq = gT[m];
                float4 val;
                float a, pc;
                a = exp2f(de.x * cA); h = fmaf(a, h, dx.x * Bq.x); pc = h * Cq.x;
                pc = DPP_ADD(pc, 0x101); pc = DPP_ADD(pc, 0x102);
                pc = DPP_ADD(pc, 0x104); pc = DPP_ADD(pc, 0x108);
                val.x = pc * gq.x;
                a = exp2f(de.y * cA); h = fmaf(a, h, dx.y * Bq.y); pc = h * Cq.y;
                pc = DPP_ADD(pc, 0x101); pc = DPP_ADD(pc, 0x102);
                pc = DPP_ADD(pc, 0x104); pc = DPP_ADD(pc, 0x108);
                val.y = pc * gq.y;
                a = exp2f(de.z * cA); h = fmaf(a, h, dx.z * Bq.z); pc = h * Cq.z;
                pc = DPP_ADD(pc, 0x101); pc = DPP_ADD(pc, 0x102);
                pc = DPP_ADD(pc, 0x104); pc = DPP_ADD(pc, 0x108);
                val.z = pc * gq.z;
                a = exp2f(de.w * cA); h = fmaf(a, h, dx.w * Bq.w); pc = h * Cq.w;
                pc = DPP_ADD(pc, 0x101); pc = DPP_ADD(pc, 0x102);
                pc = DPP_ADD(pc, 0x104); pc = DPP_ADD(pc, 0x108);
                val.w = pc * gq.w;
                if (s == 0) *reinterpret_cast<float4*>(&syT[dd][4 * m]) = val;
            }
        }
        __syncthreads();

        // ---- C: fold over own-half d, write partial ----
        {
            float acc = 0.f;
#pragma unroll
            for (int k = 0; k < 4; ++k) {
                acc += syT[j8 * 4 + k][ll8];
            }
            acc += __shfl_xor(acc, 1);
            acc += __shfl_xor(acc, 2);
            acc += __shfl_xor(acc, 4);
            if (j8 == 0) {
                int i = ibase + ll8;
                int l = dir ? (511 - i) : i;
                ypart[((c * 2 + half) * 32 + b) * 512 + l] = acc + sybase[ll8];
            }
        }
        __syncthreads();
    }
}

__global__ __launch_bounds__(256) void kfinal(const float* __restrict__ xavg,
                                              const float* __restrict__ xmax,
                                              const float* __restrict__ ypart,
                                              const float* __restrict__ gate_w,
                                              const float* __restrict__ gate_b,
                                              const float* __restrict__ out_b,
                                              float* __restrict__ out) {
    const int idx = blockIdx.x * 256 + threadIdx.x;   // 0..16383
    float xa = xavg[idx], xm = xmax[idx];
    float alpha = 1.f / (1.f + __expf(-(fmaf(xa, gate_w[0], fmaf(xm, gate_w[1], gate_b[0])))));
    float sa = ypart[0 * 16384 + idx] + ypart[1 * 16384 + idx]
             + ypart[2 * 16384 + idx] + ypart[3 * 16384 + idx];
    float sm = ypart[4 * 16384 + idx] + ypart[5 * 16384 + idx]
             + ypart[6 * 16384 + idx] + ypart[7 * 16384 + idx];
    float y = alpha * sa + (1.f - alpha) * sm + out_b[0];
    out[idx] = 1.f / (1.f + __expf(-y));
}

extern "C" void kernel_launch(void* const* d_in, const int* in_sizes, int n_in,
                              void* d_out, int out_size, void* d_ws, size_t ws_size,
                              hipStream_t stream) {
    const float* inp = (const float*)d_in[0];
    const float* paw = (const float*)d_in[1];
    const float* pab = (const float*)d_in[2];
    const float* pmw = (const float*)d_in[3];
    const float* pmb = (const float*)d_in[4];
    const float* gw  = (const float*)d_in[5];
    const float* gb  = (const float*)d_in[6];
    const float* ow  = (const float*)d_in[7];
    const float* ob  = (const float*)d_in[8];

    float* ws = (float*)d_ws;
    float* xavg = ws;
    float* xmax = ws + 16384;
    float* ypart = ws + 32768;
    float* out = (float*)d_out;

    kreduce<<<16384, 256, 0, stream>>>(inp, xavg, xmax);
    kmamba<<<256, 512, 0, stream>>>(
        xavg, xmax, ypart, paw, pab, pmw, pmb, ow,
        (const float*)d_in[9],  (const float*)d_in[10], (const float*)d_in[11],
        (const float*)d_in[12], (const float*)d_in[13], (const float*)d_in[14],
        (const float*)d_in[15], (const float*)d_in[16], (const float*)d_in[17],
        (const float*)d_in[18], (const float*)d_in[19], (const float*)d_in[20],
        (const float*)d_in[21], (const float*)d_in[22], (const float*)d_in[23],
        (const float*)d_in[24], (const float*)d_in[25], (const float*)d_in[26]);
    kfinal<<<64, 256, 0, stream>>>(xavg, xmax, ypart, gw, gb, ob, out);
}